// Round 5
// baseline (695.632 us; speedup 1.0000x reference)
//
#include <hip/hip_runtime.h>
#include <hip/hip_bf16.h>
#include <math.h>

#define SEQ  512
#define BSZ  128
#define EMBD 128
#define H4   512
#define HD   128
#define NTAG 7
#define BOSX 4
#define EOSX 5
#define NEGC (-10000.0f)

typedef _Float16 h2 __attribute__((ext_vector_type(2)));

__device__ __forceinline__ float frcp(float x) { return __builtin_amdgcn_rcpf(x); }

// f16 dot2: 2 MACs/inst, fp32 accumulate (v_dot2_f32_f16)
__device__ __forceinline__ float fdot2(h2 a, h2 b, float c) {
#if __has_builtin(__builtin_amdgcn_fdot2)
    return __builtin_amdgcn_fdot2(a, b, c, false);
#else
    return c + (float)a.x * (float)b.x + (float)a.y * (float)b.y;
#endif
}

template<int C> __device__ __forceinline__ float dppaddf(float x) {
    const int y = __builtin_amdgcn_update_dpp(0, __builtin_bit_cast(int, x), C, 0xF, 0xF, true);
    return x + __builtin_bit_cast(float, y);
}
template<int C> __device__ __forceinline__ float dppmovf(float x) {
    return __builtin_bit_cast(float,
        __builtin_amdgcn_update_dpp(0, __builtin_bit_cast(int, x), C, 0xF, 0xF, true));
}
template<int C> __device__ __forceinline__ int dppmovi(int x) {
    return __builtin_amdgcn_update_dpp(0, x, C, 0xF, 0xF, true);
}
// k = lane bits {0,1}: full k-reduce = 2 DPP stages
__device__ __forceinline__ float kreduce4(float x) {
    x = dppaddf<0xB1>(x);   // xor bit0
    x = dppaddf<0x4E>(x);   // xor bit1
    return x;
}

// f16 chunk layout: chunk k = 32 f16 = 16 dwords at dword offset 20*k.
// Within one b128 read (sub-offset 4j) the wave's 4 distinct chunk addresses
// hit disjoint bank quads {4j, 4j+20, 4j+8, 4j+28} mod 32 -> conflict-free;
// 16 lanes per address broadcast for free.
#define CH_DW  20
#define ROW_DW 80

// 32-element f16 chunk dot: w[16] half2 x x[16] half2 -> fp32
__device__ __forceinline__ float dot32h(const h2* __restrict__ w, const h2* __restrict__ x) {
    float a = 0.f;
    #pragma unroll
    for (int j = 0; j < 16; ++j) a = fdot2(w[j], x[j], a);
    return a;
}
// load 32 fp32 weights -> 16 half2 (RNE, one-time)
__device__ __forceinline__ void ldwh(h2* w, const float4* wr) {
    #pragma unroll
    for (int j = 0; j < 8; ++j) {
        const float4 f4 = wr[j];
        h2 a; a.x = (_Float16)f4.x; a.y = (_Float16)f4.y;
        h2 b; b.x = (_Float16)f4.z; b.y = (_Float16)f4.w;
        w[2 * j] = a; w[2 * j + 1] = b;
    }
}
__device__ __forceinline__ void unp16(const uint4* p, h2* x) {
    #pragma unroll
    for (int j = 0; j < 4; ++j) {
        x[4 * j]     = __builtin_bit_cast(h2, p[j].x);
        x[4 * j + 1] = __builtin_bit_cast(h2, p[j].y);
        x[4 * j + 2] = __builtin_bit_cast(h2, p[j].z);
        x[4 * j + 3] = __builtin_bit_cast(h2, p[j].w);
    }
}

// =============== K1: FUSED projection + recurrence + emissions ===============
// Round-1 structure (527 us) + proj-operand REGISTER PING-PONG PREFETCH:
// the per-step barrier makes all 8 waves flood the LDS pipe simultaneously
// (64 b128 reads/step/CU ~ 770 cyc serialized) and then VALU-burst in
// lockstep -- phases don't overlap (T_step ~ 2470 ~ sum of phases). Fix:
// x for proj row s+8 is read into VGPRs at step s-1 (ping-pong xnA/xnB,
// statically indexed by unrolled sl parity), so at barrier exit every wave
// has 64 fdot2 + DPP of guaranteed-ready work that overlaps the h-read
// LDS burst. LDS issue count unchanged; dependency burst decorrelated.
__global__ __launch_bounds__(512) __attribute__((amdgpu_waves_per_eu(2, 2)))
void bilstm_fused(const int* __restrict__ sen, const float* __restrict__ emb,
                  const float* __restrict__ Wih_f, const float* __restrict__ b_f,
                  const float* __restrict__ Wih_b, const float* __restrict__ b_b,
                  const float* __restrict__ Whh_f, const float* __restrict__ Whh_b,
                  const float* __restrict__ W_out,
                  float* __restrict__ eft, float* __restrict__ ebt)
{
    const int tid = threadIdx.x;
    const int wid = tid >> 6;
    const int lane = tid & 63;
    const int k = lane & 3;                                // K-chunk / owned gate q
    const int m = lane >> 2;                               // 0..15
    const int u = wid * 16 + m;
    const bool bk0 = (lane & 1) != 0;
    const bool bk1 = (lane & 2) != 0;
    const int chain = blockIdx.x;
    const int dir = chain & 1;
    const int b = chain >> 1;
    const int t0 = dir ? (SEQ - 1) : 0;
    const int ts = dir ? -1 : 1;

    __shared__ __align__(16) unsigned xs[2][8 * ROW_DW];   // x-stage dbuf (f16 chunks), 5 KB
    __shared__ __align__(16) unsigned hdb_u[2 * ROW_DW];   // h double-buffer, f16 chunks

    const float* __restrict__ Wih  = dir ? Wih_b : Wih_f;
    const float* __restrict__ Whh  = dir ? Whh_b : Whh_f;
    const float* __restrict__ bias = dir ? b_b  : b_f;

    h2 wih[4][16], whh[4][16], wo[16];
    #pragma unroll
    for (int g = 0; g < 4; ++g) {
        ldwh(wih[g], (const float4*)(Wih + (g * HD + u) * EMBD + k * 32));
        ldwh(whh[g], (const float4*)(Whh + (g * HD + u) * HD + k * 32));
    }
    {
        const int mm = (m < NTAG) ? m : 0;
        ldwh(wo, (const float4*)(W_out + mm * 256 + dir * HD + k * 32));
    }
    const float bj = bias[k * HD + u];                     // my gate's bias

    if (tid < 2 * ROW_DW) hdb_u[tid] = 0u;                 // h=0

    // ---- staging: window w = logical rows [8w, 8w+8); wave srow stages row
    // 8w+srow, lane sp loads float2 -> one f16 dword of the chunk layout ----
    const int srow = wid;
    const int sp = lane;
    const int sdst = srow * ROW_DW + (sp >> 4) * CH_DW + (sp & 15);

    float2 sv;                                             // in-flight window regs
    auto sissue = [&](int w) {
        const int row = w * 8 + srow;
        const int tg = t0 + ts * row;
        const int tok = sen[tg * BSZ + b];
        sv = *(const float2*)(emb + (size_t)tok * EMBD + 2 * sp);
    };
    auto swrite = [&](int buf) {
        h2 t; t.x = (_Float16)sv.x; t.y = (_Float16)sv.y;
        xs[buf][sdst] = __builtin_bit_cast(unsigned, t);
    };

    float zf[8];                                           // xw FIFO (gate k, unit u)
    float c = 0.0f, v0 = 0.0f, v1 = 0.0f, v2 = 0.0f, v3 = 0.0f;
    float* __restrict__ eX = (dir ? ebt : eft) + (size_t)b * (SEQ * 8);

    // ---- prologue: windows 0,1 staged; zf[0..7] (rows 0..7); window 2 in flight
    sissue(0); swrite(0);
    sissue(1); swrite(1);
    __syncthreads();
    uint4 xnA[4], xnB[4];                                  // proj-x ping-pong regs
    {   // preload x row 8 (window 1 = buffer 1, offset 0) for step 0's proj
        const uint4* xr = (const uint4*)(xs[1] + k * CH_DW);
        #pragma unroll
        for (int j = 0; j < 4; ++j) xnA[j] = xr[j];
    }
    #pragma unroll
    for (int r = 0; r < 8; ++r) {
        const uint4* xr = (const uint4*)(xs[0] + r * ROW_DW + k * CH_DW);
        uint4 pk[4];
        #pragma unroll
        for (int j = 0; j < 4; ++j) pk[j] = xr[j];
        h2 px[16];
        unp16(pk, px);
        const float pi = dot32h(wih[0], px);
        const float pf = dot32h(wih[1], px);
        const float pg = dot32h(wih[2], px);
        const float po = dot32h(wih[3], px);
        const float A = (bk0 ? pf : pi) + dppmovf<0xB1>(bk0 ? pi : pf);
        const float B = (bk0 ? po : pg) + dppmovf<0x4E>(bk0 ? pg : po);
        const float z = (bk1 ? B : A) + dppmovf<0x4E>(bk1 ? A : B);
        zf[r] = z + bj;
    }
    sissue(2);                                             // rows [16,24) in flight
    __syncthreads();                                       // xs[0] reads done before s=0 rewrite

    // ---- main loop: 64 blocks of 8 steps ----
    for (int base = 0; base < SEQ; base += 8) {
        #pragma unroll
        for (int sl = 0; sl < 8; ++sl) {
            const int s = base + sl;
            const int cur = sl & 1;                        // base is even -> s&1 == sl&1
            uint4* xc = (sl & 1) ? xnB : xnA;              // row s+8 (prefetched)
            uint4* xo = (sl & 1) ? xnA : xnB;              // dest for row s+9
            if (sl == 0) {
                // write window base/8+2 (rows [base+16,base+24)) -> buf (base>>3)&1;
                // readers this window use the other buf; last reader of this buf
                // was step base-1 (barrier-separated).
                if (base <= SEQ - 24) swrite((base >> 3) & 1);
                if (base <= SEQ - 32) sissue((base >> 3) + 3);   // rows [base+24,base+32)
            }
            // issue h-read for this step (waited in rec below)
            uint4 hpk[4];
            {
                const uint4* hr = (const uint4*)(hdb_u + cur * ROW_DW + k * CH_DW);
                #pragma unroll
                for (int j = 0; j < 4; ++j) hpk[j] = hr[j];
            }
            // issue x-read for NEXT step's proj (row s+9; no waiter this step).
            // sl<7: window W+1 (other buffer, untouched); sl==7: window W+2,
            // swritten at sl==0 of this block, barrier-separated -> visible.
            if (s + 9 < SEQ) {
                const int rr = s + 9;
                const uint4* xr = (const uint4*)(xs[(rr >> 3) & 1] + (rr & 7) * ROW_DW + k * CH_DW);
                #pragma unroll
                for (int j = 0; j < 4; ++j) xo[j] = xr[j];
            }
            const float xq = zf[sl];                       // xw for THIS step (made at s-8)
            // projection for row s+8 on PREFETCHED regs: issues at barrier
            // exit with zero LDS dependency, overlapping the h-read burst.
            if (s < SEQ - 8) {
                h2 px[16];
                unp16(xc, px);
                const float pi = dot32h(wih[0], px);
                const float pf = dot32h(wih[1], px);
                const float pg = dot32h(wih[2], px);
                const float po = dot32h(wih[3], px);
                const float A = (bk0 ? pf : pi) + dppmovf<0xB1>(bk0 ? pi : pf);
                const float B = (bk0 ? po : pg) + dppmovf<0x4E>(bk0 ? pg : po);
                const float z = (bk1 ? B : A) + dppmovf<0x4E>(bk1 ? A : B);
                zf[sl] = z + bj;
            }
            // recurrence (first use of hpk -> compiler places counted lgkm wait)
            h2 hx[16];
            unp16(hpk, hx);
            {
                const float pi = dot32h(whh[0], hx);
                const float pf = dot32h(whh[1], hx);
                const float pg = dot32h(whh[2], hx);
                const float po = dot32h(whh[3], hx);
                const float A = (bk0 ? pf : pi) + dppmovf<0xB1>(bk0 ? pi : pf);
                const float B = (bk0 ? po : pg) + dppmovf<0x4E>(bk0 ? pg : po);
                float z = (bk1 ? B : A) + dppmovf<0x4E>(bk1 ? A : B);
                z += xq;
                // one activation per lane (gate 2 = tanh via 2*sigma(2z)-1)
                const bool isg = bk1 && !bk0;
                const float x2 = isg ? (z + z) : z;
                float y = frcp(1.0f + __expf(-x2));
                y = isg ? (2.0f * y - 1.0f) : y;
                // all-gather the 4 activated gates
                const float r1 = dppmovf<0xB1>(y);
                const float r2 = dppmovf<0x4E>(y);
                const float r3 = dppmovf<0x4E>(r1);
                const float i0 = bk0 ? r1 : y,  i1 = bk0 ? y : r1;
                const float i2 = bk0 ? r3 : r2, i3 = bk0 ? r2 : r3;
                const float gi = bk1 ? i2 : i0;
                const float gf = bk1 ? i3 : i1;
                const float gg = bk1 ? i0 : i2;
                const float go = bk1 ? i1 : i3;
                c = gf * c + gi * gg;                      // redundant across 4 k-lanes
                const float th = 2.0f * frcp(1.0f + __expf(-2.0f * c)) - 1.0f;
                const float h = go * th;
                if (k == 0) {                              // write h as f16 halfword
                    ((unsigned short*)hdb_u)[((cur ^ 1) * ROW_DW + (u >> 5) * CH_DW) * 2 + (u & 31)]
                        = __builtin_bit_cast(unsigned short, (_Float16)h);
                }
            }
            if (wid == 0 && s >= 1) {                      // emission for time e = s-1
                const float ev = kreduce4(dot32h(wo, hx));
                const int e = s - 1;
                const bool mine = (e & 3) == k;            // e uniform, k lane-varying
                const int j = (e >> 2) & 3;
                v0 = (mine && j == 0) ? ev : v0;
                v1 = (mine && j == 1) ? ev : v1;
                v2 = (mine && j == 2) ? ev : v2;
                v3 = (mine && j == 3) ? ev : v3;
                if ((s & 15) == 0 && m < NTAG) {           // flush e in [s-16, s-1]
                    const int eA = s - 16 + k;
                    eX[(t0 + ts * (eA +  0)) * 8 + m] = v0;
                    eX[(t0 + ts * (eA +  4)) * 8 + m] = v1;
                    eX[(t0 + ts * (eA +  8)) * 8 + m] = v2;
                    eX[(t0 + ts * (eA + 12)) * 8 + m] = v3;
                }
            }
            __syncthreads();
        }
    }

    // ---- epilogue: s = SEQ -> emission e = SEQ-1 + final flush ----
    {
        h2 hx[16];                                         // h_{last} from hdb[0]
        const uint4* hr = (const uint4*)(hdb_u + k * CH_DW);
        uint4 pk[4];
        #pragma unroll
        for (int j = 0; j < 4; ++j) pk[j] = hr[j];
        unp16(pk, hx);
        if (wid == 0) {
            const float ev = kreduce4(dot32h(wo, hx));
            if (k == 3) v3 = ev;                           // e=511: (e&3)=3, (e>>2)&3=3
            if (m < NTAG) {
                const int eA = SEQ - 16 + k;
                eX[(t0 + ts * (eA +  0)) * 8 + m] = v0;
                eX[(t0 + ts * (eA +  4)) * 8 + m] = v1;
                eX[(t0 + ts * (eA +  8)) * 8 + m] = v2;
                eX[(t0 + ts * (eA + 12)) * 8 + m] = v3;
            }
        }
    }
}

// ======================= K2: Viterbi scan + backtrace =======================
// (verbatim round-4 kernel: DPP butterfly argmax, OR-packed 3-bit
// backpointer words, readlane-only bit-chase backtrace)
__global__ __launch_bounds__(256, 1)
void vit_kernel(const float* __restrict__ eft, const float* __restrict__ ebt,
                const float* __restrict__ b_out, const float* __restrict__ trans,
                float* __restrict__ out)
{
    const int b = blockIdx.x;
    const int tid = threadIdx.x;
    __shared__ __align__(16) float ftl[SEQ * 8];
    __shared__ unsigned wordL[SEQ];                        // packed backpointers

    {   // stage ef+eb with all 256 threads
        const float4* sf = (const float4*)(eft + (size_t)b * (SEQ * 8));
        const float4* sb = (const float4*)(ebt + (size_t)b * (SEQ * 8));
        float4* dst = (float4*)ftl;
        #pragma unroll
        for (int i = 0; i < SEQ * 2 / 256; ++i) {
            const int idx = tid + i * 256;
            float4 a = sf[idx];
            const float4 c4 = sb[idx];
            a.x += c4.x; a.y += c4.y; a.z += c4.z; a.w += c4.w;
            dst[idx] = a;
        }
    }
    __syncthreads();

    if (tid < 64) {
        const int lane = tid;
        const int next = lane >> 3;
        const int prev = lane & 7;
        const bool pv = (prev < NTAG);
        const bool nv = (next < NTAG);
        const float trv = (pv && nv) ? (trans[next * NTAG + prev] + b_out[next]) : -3.0e38f;
        float fvp = pv ? ((prev == BOSX) ? 0.0f : NEGC) : -3.0e38f;

        // (max, first-index) combiner is associative+commutative ->
        // any butterfly pairing gives results identical to the shfl version.
        for (int t = 0; t < SEQ; ++t) {
            float mv = fvp + trv;
            int am = prev;
            {   // xor1 (quad_perm)
                const float om = dppmovf<0xB1>(mv); const int oa = dppmovi<0xB1>(am);
                if (om > mv || (om == mv && oa < am)) { mv = om; am = oa; }
            }
            {   // xor2 (quad_perm)
                const float om = dppmovf<0x4E>(mv); const int oa = dppmovi<0x4E>(am);
                if (om > mv || (om == mv && oa < am)) { mv = om; am = oa; }
            }
            {   // quad-pair via row_half_mirror (value quad-uniform by now)
                const float om = dppmovf<0x141>(mv); const int oa = dppmovi<0x141>(am);
                if (om > mv || (om == mv && oa < am)) { mv = om; am = oa; }
            }
            const float fvnew = mv + ftl[t * 8 + next];
            // transpose: fvp[lane] = fvnew(next = prev(lane)); same pattern
            // gathers am so lane holds bptr[next = prev(lane)]
            const float nfv = __shfl(fvnew, (lane & 7) << 3);
            const int   amg = __shfl(am,    (lane & 7) << 3);
            unsigned pw = (unsigned)amg << (3 * prev);     // field for next = prev(lane)
            pw |= (unsigned)dppmovi<0xB1>((int)pw);
            pw |= (unsigned)dppmovi<0x4E>((int)pw);
            pw |= (unsigned)dppmovi<0x141>((int)pw);
            if (lane == 0) wordL[t] = pw;
            fvp = pv ? nfv : -3.0e38f;
        }

        float term = pv ? (fvp + trans[EOSX * NTAG + prev]) : -3.0e38f;
        int am = prev;
        {
            const float om = dppmovf<0xB1>(term); const int oa = dppmovi<0xB1>(am);
            if (om > term || (om == term && oa < am)) { term = om; am = oa; }
        }
        {
            const float om = dppmovf<0x4E>(term); const int oa = dppmovi<0x4E>(am);
            if (om > term || (om == term && oa < am)) { term = om; am = oa; }
        }
        {
            const float om = dppmovf<0x141>(term); const int oa = dppmovi<0x141>(am);
            if (om > term || (om == term && oa < am)) { term = om; am = oa; }
        }
        if (lane == 0) out[b] = term;

        // ---- backtrace: preload packed words, uniform readlane bit-chase ----
        unsigned wd[8];
        #pragma unroll
        for (int c2 = 0; c2 < 8; ++c2) wd[c2] = wordL[c2 * 64 + lane];
        int cur = __builtin_amdgcn_readfirstlane(am);      // uniform terminal tag
        unsigned pr[8];
        #pragma unroll
        for (int c2 = 7; c2 >= 0; --c2) {                  // unrolled: wd/pr static-indexed
            unsigned acc = 0u;
            for (int tt = 63; tt >= 0; --tt) {             // t = c2*64 + tt, descending
                acc = (lane == tt) ? (unsigned)cur : acc;  // path[t] = cur
                const unsigned w = (unsigned)__builtin_amdgcn_readlane((int)wd[c2], tt);
                cur = (int)((w >> (3 * cur)) & 7u);        // cur = bptr[t][cur]
            }
            pr[c2] = acc;
        }
        #pragma unroll
        for (int c2 = 0; c2 < 8; ++c2)
            out[BSZ + (c2 * 64 + lane) * BSZ + b] = (float)pr[c2];
    }
}

// ======================= launch =======================
extern "C" void kernel_launch(void* const* d_in, const int* in_sizes, int n_in,
                              void* d_out, int out_size, void* d_ws, size_t ws_size,
                              hipStream_t stream)
{
    const int*   sen   = (const int*)d_in[0];
    const float* emb   = (const float*)d_in[1];
    const float* Wih_f = (const float*)d_in[2];
    const float* Whh_f = (const float*)d_in[3];
    const float* b_f   = (const float*)d_in[4];
    const float* Wih_b = (const float*)d_in[5];
    const float* Whh_b = (const float*)d_in[6];
    const float* b_b   = (const float*)d_in[7];
    const float* W_out = (const float*)d_in[8];
    const float* b_out = (const float*)d_in[9];
    const float* trans = (const float*)d_in[10];
    float* out = (float*)d_out;

    char* ws = (char*)d_ws;
    const size_t ft_bytes = (size_t)BSZ * SEQ * 8 * 4;    // 2 MB each
    float* eft = (float*)ws;
    float* ebt = (float*)(ws + ft_bytes);

    bilstm_fused<<<dim3(2 * BSZ), dim3(512), 0, stream>>>(
        sen, emb, Wih_f, b_f, Wih_b, b_b, Whh_f, Whh_b, W_out, eft, ebt);
    vit_kernel<<<dim3(BSZ), dim3(256), 0, stream>>>(eft, ebt, b_out, trans, out);
}

// Round 6
// 694.881 us; speedup vs baseline: 1.0011x; 1.0011x over previous
//
#include <hip/hip_runtime.h>
#include <hip/hip_bf16.h>
#include <math.h>

#define SEQ  512
#define BSZ  128
#define EMBD 128
#define H4   512
#define HD   128
#define NTAG 7
#define BOSX 4
#define EOSX 5
#define NEGC (-10000.0f)

typedef _Float16 h2 __attribute__((ext_vector_type(2)));

__device__ __forceinline__ float frcp(float x) { return __builtin_amdgcn_rcpf(x); }

// f16 dot2: 2 MACs/inst, fp32 accumulate (v_dot2_f32_f16)
__device__ __forceinline__ float fdot2(h2 a, h2 b, float c) {
#if __has_builtin(__builtin_amdgcn_fdot2)
    return __builtin_amdgcn_fdot2(a, b, c, false);
#else
    return c + (float)a.x * (float)b.x + (float)a.y * (float)b.y;
#endif
}

template<int C> __device__ __forceinline__ float dppaddf(float x) {
    const int y = __builtin_amdgcn_update_dpp(0, __builtin_bit_cast(int, x), C, 0xF, 0xF, true);
    return x + __builtin_bit_cast(float, y);
}
template<int C> __device__ __forceinline__ float dppmovf(float x) {
    return __builtin_bit_cast(float,
        __builtin_amdgcn_update_dpp(0, __builtin_bit_cast(int, x), C, 0xF, 0xF, true));
}
template<int C> __device__ __forceinline__ int dppmovi(int x) {
    return __builtin_amdgcn_update_dpp(0, x, C, 0xF, 0xF, true);
}
// k = lane bits {0,1}: full k-reduce = 2 DPP stages
__device__ __forceinline__ float kreduce4(float x) {
    x = dppaddf<0xB1>(x);   // xor bit0
    x = dppaddf<0x4E>(x);   // xor bit1
    return x;
}

// f16 chunk layout: chunk k = 32 f16 = 16 dwords at dword offset 20*k.
// Within one b128 read (sub-offset 4j) the wave's 4 distinct chunk addresses
// hit disjoint bank quads {4j, 4j+20, 4j+8, 4j+28} mod 32 -> conflict-free;
// 16 lanes per address broadcast for free.
#define CH_DW  20
#define ROW_DW 80

// 32-element f16 chunk dot: w[16] half2 x x[16] half2 -> fp32
__device__ __forceinline__ float dot32h(const h2* __restrict__ w, const h2* __restrict__ x) {
    float a = 0.f;
    #pragma unroll
    for (int j = 0; j < 16; ++j) a = fdot2(w[j], x[j], a);
    return a;
}
// load 32 fp32 weights -> 16 half2 (RNE, one-time)
__device__ __forceinline__ void ldwh(h2* w, const float4* wr) {
    #pragma unroll
    for (int j = 0; j < 8; ++j) {
        const float4 f4 = wr[j];
        h2 a; a.x = (_Float16)f4.x; a.y = (_Float16)f4.y;
        h2 b; b.x = (_Float16)f4.z; b.y = (_Float16)f4.w;
        w[2 * j] = a; w[2 * j + 1] = b;
    }
}
__device__ __forceinline__ void unp16(const uint4* p, h2* x) {
    #pragma unroll
    for (int j = 0; j < 4; ++j) {
        x[4 * j]     = __builtin_bit_cast(h2, p[j].x);
        x[4 * j + 1] = __builtin_bit_cast(h2, p[j].y);
        x[4 * j + 2] = __builtin_bit_cast(h2, p[j].z);
        x[4 * j + 3] = __builtin_bit_cast(h2, p[j].w);
    }
}

// =============== K1: FUSED projection + recurrence + emissions ===============
// Round-1 body. ONE change: amdgpu_waves_per_eu(1,2) instead of (2,2).
// Resource arithmetic: weights alone = 144 VGPRs (wih 64 + whh 64 + wo 16),
// but (2,2) builds reported VGPR_Count=128 -> weights were NOT resident;
// WRITE_SIZE excess (~21 MB = ~160 B/block/step) + FETCH excess (~15 MB)
// = per-step scratch spill round-trip, force-drained by the pre-barrier
// vmcnt(0) every step. (1,2) relaxes the allocator budget so the ~220-reg
// working set is fully arch-resident (2 x 220 < 512/SIMD -> hardware still
// places 2 waves/SIMD). No other K1 change: clean A/B on the attribute.
__global__ __launch_bounds__(512) __attribute__((amdgpu_waves_per_eu(1, 2)))
void bilstm_fused(const int* __restrict__ sen, const float* __restrict__ emb,
                  const float* __restrict__ Wih_f, const float* __restrict__ b_f,
                  const float* __restrict__ Wih_b, const float* __restrict__ b_b,
                  const float* __restrict__ Whh_f, const float* __restrict__ Whh_b,
                  const float* __restrict__ W_out,
                  float* __restrict__ eft, float* __restrict__ ebt)
{
    const int tid = threadIdx.x;
    const int wid = tid >> 6;
    const int lane = tid & 63;
    const int k = lane & 3;                                // K-chunk / owned gate q
    const int m = lane >> 2;                               // 0..15
    const int u = wid * 16 + m;
    const bool bk0 = (lane & 1) != 0;
    const bool bk1 = (lane & 2) != 0;
    const int chain = blockIdx.x;
    const int dir = chain & 1;
    const int b = chain >> 1;
    const int t0 = dir ? (SEQ - 1) : 0;
    const int ts = dir ? -1 : 1;

    __shared__ __align__(16) unsigned xs[2][8 * ROW_DW];   // x-stage dbuf (f16 chunks), 5 KB
    __shared__ __align__(16) unsigned hdb_u[2 * ROW_DW];   // h double-buffer, f16 chunks

    const float* __restrict__ Wih  = dir ? Wih_b : Wih_f;
    const float* __restrict__ Whh  = dir ? Whh_b : Whh_f;
    const float* __restrict__ bias = dir ? b_b  : b_f;

    h2 wih[4][16], whh[4][16], wo[16];
    #pragma unroll
    for (int g = 0; g < 4; ++g) {
        ldwh(wih[g], (const float4*)(Wih + (g * HD + u) * EMBD + k * 32));
        ldwh(whh[g], (const float4*)(Whh + (g * HD + u) * HD + k * 32));
    }
    {
        const int mm = (m < NTAG) ? m : 0;
        ldwh(wo, (const float4*)(W_out + mm * 256 + dir * HD + k * 32));
    }
    const float bj = bias[k * HD + u];                     // my gate's bias

    if (tid < 2 * ROW_DW) hdb_u[tid] = 0u;                 // h=0

    // ---- staging: window w = logical rows [8w, 8w+8); wave srow stages row
    // 8w+srow, lane sp loads float2 -> one f16 dword of the chunk layout ----
    const int srow = wid;
    const int sp = lane;
    const int sdst = srow * ROW_DW + (sp >> 4) * CH_DW + (sp & 15);

    float2 sv;                                             // in-flight window regs
    auto sissue = [&](int w) {
        const int row = w * 8 + srow;
        const int tg = t0 + ts * row;
        const int tok = sen[tg * BSZ + b];
        sv = *(const float2*)(emb + (size_t)tok * EMBD + 2 * sp);
    };
    auto swrite = [&](int buf) {
        h2 t; t.x = (_Float16)sv.x; t.y = (_Float16)sv.y;
        xs[buf][sdst] = __builtin_bit_cast(unsigned, t);
    };

    float zf[8];                                           // xw FIFO (gate k, unit u)
    float c = 0.0f, v0 = 0.0f, v1 = 0.0f, v2 = 0.0f, v3 = 0.0f;
    float* __restrict__ eX = (dir ? ebt : eft) + (size_t)b * (SEQ * 8);

    // ---- prologue: windows 0,1 staged; zf[0..7] (rows 0..7); window 2 in flight
    sissue(0); swrite(0);
    sissue(1); swrite(1);
    __syncthreads();
    #pragma unroll
    for (int r = 0; r < 8; ++r) {
        const uint4* xr = (const uint4*)(xs[0] + r * ROW_DW + k * CH_DW);
        uint4 pk[4];
        #pragma unroll
        for (int j = 0; j < 4; ++j) pk[j] = xr[j];
        h2 px[16];
        unp16(pk, px);
        const float pi = dot32h(wih[0], px);
        const float pf = dot32h(wih[1], px);
        const float pg = dot32h(wih[2], px);
        const float po = dot32h(wih[3], px);
        const float A = (bk0 ? pf : pi) + dppmovf<0xB1>(bk0 ? pi : pf);
        const float B = (bk0 ? po : pg) + dppmovf<0x4E>(bk0 ? pg : po);
        const float z = (bk1 ? B : A) + dppmovf<0x4E>(bk1 ? A : B);
        zf[r] = z + bj;
    }
    sissue(2);                                             // rows [16,24) in flight
    __syncthreads();                                       // xs[0] reads done before s=0 rewrite

    // ---- main loop: 64 blocks of 8 steps ----
    for (int base = 0; base < SEQ; base += 8) {
        #pragma unroll
        for (int sl = 0; sl < 8; ++sl) {
            const int s = base + sl;
            const int cur = sl & 1;                        // base is even -> s&1 == sl&1
            // chunk k of h_{t-ts} (f16)
            h2 hx[16];
            {
                const uint4* hr = (const uint4*)(hdb_u + cur * ROW_DW + k * CH_DW);
                uint4 pk[4];
                #pragma unroll
                for (int j = 0; j < 4; ++j) pk[j] = hr[j];
                unp16(pk, hx);
            }
            if (sl == 0) {
                // write window base/8+2 (rows [base+16,base+24)) -> buf (base>>3)&1;
                // readers this window use the other buf; last reader of this buf
                // was step base-1 (barrier-separated).
                if (base <= SEQ - 24) swrite((base >> 3) & 1);
                if (base <= SEQ - 32) sissue((base >> 3) + 3);   // rows [base+24,base+32)
            }
            const float xq = zf[sl];                       // xw for THIS step (made at s-8)
            // projection for row s+8 (fills recurrence stall slots)
            if (s < SEQ - 8) {
                const uint4* xr = (const uint4*)(xs[((base >> 3) + 1) & 1] + sl * ROW_DW + k * CH_DW);
                uint4 pk[4];
                #pragma unroll
                for (int j = 0; j < 4; ++j) pk[j] = xr[j];
                h2 px[16];
                unp16(pk, px);
                const float pi = dot32h(wih[0], px);
                const float pf = dot32h(wih[1], px);
                const float pg = dot32h(wih[2], px);
                const float po = dot32h(wih[3], px);
                const float A = (bk0 ? pf : pi) + dppmovf<0xB1>(bk0 ? pi : pf);
                const float B = (bk0 ? po : pg) + dppmovf<0x4E>(bk0 ? pg : po);
                const float z = (bk1 ? B : A) + dppmovf<0x4E>(bk1 ? A : B);
                zf[sl] = z + bj;
            }
            // recurrence
            {
                const float pi = dot32h(whh[0], hx);
                const float pf = dot32h(whh[1], hx);
                const float pg = dot32h(whh[2], hx);
                const float po = dot32h(whh[3], hx);
                const float A = (bk0 ? pf : pi) + dppmovf<0xB1>(bk0 ? pi : pf);
                const float B = (bk0 ? po : pg) + dppmovf<0x4E>(bk0 ? pg : po);
                float z = (bk1 ? B : A) + dppmovf<0x4E>(bk1 ? A : B);
                z += xq;
                // one activation per lane (gate 2 = tanh via 2*sigma(2z)-1)
                const bool isg = bk1 && !bk0;
                const float x2 = isg ? (z + z) : z;
                float y = frcp(1.0f + __expf(-x2));
                y = isg ? (2.0f * y - 1.0f) : y;
                // all-gather the 4 activated gates
                const float r1 = dppmovf<0xB1>(y);
                const float r2 = dppmovf<0x4E>(y);
                const float r3 = dppmovf<0x4E>(r1);
                const float i0 = bk0 ? r1 : y,  i1 = bk0 ? y : r1;
                const float i2 = bk0 ? r3 : r2, i3 = bk0 ? r2 : r3;
                const float gi = bk1 ? i2 : i0;
                const float gf = bk1 ? i3 : i1;
                const float gg = bk1 ? i0 : i2;
                const float go = bk1 ? i1 : i3;
                c = gf * c + gi * gg;                      // redundant across 4 k-lanes
                const float th = 2.0f * frcp(1.0f + __expf(-2.0f * c)) - 1.0f;
                const float h = go * th;
                if (k == 0) {                              // write h as f16 halfword
                    ((unsigned short*)hdb_u)[((cur ^ 1) * ROW_DW + (u >> 5) * CH_DW) * 2 + (u & 31)]
                        = __builtin_bit_cast(unsigned short, (_Float16)h);
                }
            }
            if (wid == 0 && s >= 1) {                      // emission for time e = s-1
                const float ev = kreduce4(dot32h(wo, hx));
                const int e = s - 1;
                const bool mine = (e & 3) == k;            // e uniform, k lane-varying
                const int j = (e >> 2) & 3;
                v0 = (mine && j == 0) ? ev : v0;
                v1 = (mine && j == 1) ? ev : v1;
                v2 = (mine && j == 2) ? ev : v2;
                v3 = (mine && j == 3) ? ev : v3;
                if ((s & 15) == 0 && m < NTAG) {           // flush e in [s-16, s-1]
                    const int eA = s - 16 + k;
                    eX[(t0 + ts * (eA +  0)) * 8 + m] = v0;
                    eX[(t0 + ts * (eA +  4)) * 8 + m] = v1;
                    eX[(t0 + ts * (eA +  8)) * 8 + m] = v2;
                    eX[(t0 + ts * (eA + 12)) * 8 + m] = v3;
                }
            }
            __syncthreads();
        }
    }

    // ---- epilogue: s = SEQ -> emission e = SEQ-1 + final flush ----
    {
        h2 hx[16];                                         // h_{last} from hdb[0]
        const uint4* hr = (const uint4*)(hdb_u + k * CH_DW);
        uint4 pk[4];
        #pragma unroll
        for (int j = 0; j < 4; ++j) pk[j] = hr[j];
        unp16(pk, hx);
        if (wid == 0) {
            const float ev = kreduce4(dot32h(wo, hx));
            if (k == 3) v3 = ev;                           // e=511: (e&3)=3, (e>>2)&3=3
            if (m < NTAG) {
                const int eA = SEQ - 16 + k;
                eX[(t0 + ts * (eA +  0)) * 8 + m] = v0;
                eX[(t0 + ts * (eA +  4)) * 8 + m] = v1;
                eX[(t0 + ts * (eA +  8)) * 8 + m] = v2;
                eX[(t0 + ts * (eA + 12)) * 8 + m] = v3;
            }
        }
    }
}

// ======================= K2: Viterbi scan + backtrace =======================
// (verbatim round-4 kernel: DPP butterfly argmax, OR-packed 3-bit
// backpointer words, readlane-only bit-chase backtrace)
__global__ __launch_bounds__(256, 1)
void vit_kernel(const float* __restrict__ eft, const float* __restrict__ ebt,
                const float* __restrict__ b_out, const float* __restrict__ trans,
                float* __restrict__ out)
{
    const int b = blockIdx.x;
    const int tid = threadIdx.x;
    __shared__ __align__(16) float ftl[SEQ * 8];
    __shared__ unsigned wordL[SEQ];                        // packed backpointers

    {   // stage ef+eb with all 256 threads
        const float4* sf = (const float4*)(eft + (size_t)b * (SEQ * 8));
        const float4* sb = (const float4*)(ebt + (size_t)b * (SEQ * 8));
        float4* dst = (float4*)ftl;
        #pragma unroll
        for (int i = 0; i < SEQ * 2 / 256; ++i) {
            const int idx = tid + i * 256;
            float4 a = sf[idx];
            const float4 c4 = sb[idx];
            a.x += c4.x; a.y += c4.y; a.z += c4.z; a.w += c4.w;
            dst[idx] = a;
        }
    }
    __syncthreads();

    if (tid < 64) {
        const int lane = tid;
        const int next = lane >> 3;
        const int prev = lane & 7;
        const bool pv = (prev < NTAG);
        const bool nv = (next < NTAG);
        const float trv = (pv && nv) ? (trans[next * NTAG + prev] + b_out[next]) : -3.0e38f;
        float fvp = pv ? ((prev == BOSX) ? 0.0f : NEGC) : -3.0e38f;

        // (max, first-index) combiner is associative+commutative ->
        // any butterfly pairing gives results identical to the shfl version.
        for (int t = 0; t < SEQ; ++t) {
            float mv = fvp + trv;
            int am = prev;
            {   // xor1 (quad_perm)
                const float om = dppmovf<0xB1>(mv); const int oa = dppmovi<0xB1>(am);
                if (om > mv || (om == mv && oa < am)) { mv = om; am = oa; }
            }
            {   // xor2 (quad_perm)
                const float om = dppmovf<0x4E>(mv); const int oa = dppmovi<0x4E>(am);
                if (om > mv || (om == mv && oa < am)) { mv = om; am = oa; }
            }
            {   // quad-pair via row_half_mirror (value quad-uniform by now)
                const float om = dppmovf<0x141>(mv); const int oa = dppmovi<0x141>(am);
                if (om > mv || (om == mv && oa < am)) { mv = om; am = oa; }
            }
            const float fvnew = mv + ftl[t * 8 + next];
            // transpose: fvp[lane] = fvnew(next = prev(lane)); same pattern
            // gathers am so lane holds bptr[next = prev(lane)]
            const float nfv = __shfl(fvnew, (lane & 7) << 3);
            const int   amg = __shfl(am,    (lane & 7) << 3);
            unsigned pw = (unsigned)amg << (3 * prev);     // field for next = prev(lane)
            pw |= (unsigned)dppmovi<0xB1>((int)pw);
            pw |= (unsigned)dppmovi<0x4E>((int)pw);
            pw |= (unsigned)dppmovi<0x141>((int)pw);
            if (lane == 0) wordL[t] = pw;
            fvp = pv ? nfv : -3.0e38f;
        }

        float term = pv ? (fvp + trans[EOSX * NTAG + prev]) : -3.0e38f;
        int am = prev;
        {
            const float om = dppmovf<0xB1>(term); const int oa = dppmovi<0xB1>(am);
            if (om > term || (om == term && oa < am)) { term = om; am = oa; }
        }
        {
            const float om = dppmovf<0x4E>(term); const int oa = dppmovi<0x4E>(am);
            if (om > term || (om == term && oa < am)) { term = om; am = oa; }
        }
        {
            const float om = dppmovf<0x141>(term); const int oa = dppmovi<0x141>(am);
            if (om > term || (om == term && oa < am)) { term = om; am = oa; }
        }
        if (lane == 0) out[b] = term;

        // ---- backtrace: preload packed words, uniform readlane bit-chase ----
        unsigned wd[8];
        #pragma unroll
        for (int c2 = 0; c2 < 8; ++c2) wd[c2] = wordL[c2 * 64 + lane];
        int cur = __builtin_amdgcn_readfirstlane(am);      // uniform terminal tag
        unsigned pr[8];
        #pragma unroll
        for (int c2 = 7; c2 >= 0; --c2) {                  // unrolled: wd/pr static-indexed
            unsigned acc = 0u;
            for (int tt = 63; tt >= 0; --tt) {             // t = c2*64 + tt, descending
                acc = (lane == tt) ? (unsigned)cur : acc;  // path[t] = cur
                const unsigned w = (unsigned)__builtin_amdgcn_readlane((int)wd[c2], tt);
                cur = (int)((w >> (3 * cur)) & 7u);        // cur = bptr[t][cur]
            }
            pr[c2] = acc;
        }
        #pragma unroll
        for (int c2 = 0; c2 < 8; ++c2)
            out[BSZ + (c2 * 64 + lane) * BSZ + b] = (float)pr[c2];
    }
}

// ======================= launch =======================
extern "C" void kernel_launch(void* const* d_in, const int* in_sizes, int n_in,
                              void* d_out, int out_size, void* d_ws, size_t ws_size,
                              hipStream_t stream)
{
    const int*   sen   = (const int*)d_in[0];
    const float* emb   = (const float*)d_in[1];
    const float* Wih_f = (const float*)d_in[2];
    const float* Whh_f = (const float*)d_in[3];
    const float* b_f   = (const float*)d_in[4];
    const float* Wih_b = (const float*)d_in[5];
    const float* Whh_b = (const float*)d_in[6];
    const float* b_b   = (const float*)d_in[7];
    const float* W_out = (const float*)d_in[8];
    const float* b_out = (const float*)d_in[9];
    const float* trans = (const float*)d_in[10];
    float* out = (float*)d_out;

    char* ws = (char*)d_ws;
    const size_t ft_bytes = (size_t)BSZ * SEQ * 8 * 4;    // 2 MB each
    float* eft = (float*)ws;
    float* ebt = (float*)(ws + ft_bytes);

    bilstm_fused<<<dim3(2 * BSZ), dim3(512), 0, stream>>>(
        sen, emb, Wih_f, b_f, Wih_b, b_b, Whh_f, Whh_b, W_out, eft, ebt);
    vit_kernel<<<dim3(BSZ), dim3(256), 0, stream>>>(eft, ebt, b_out, trans, out);
}

// Round 7
// 554.781 us; speedup vs baseline: 1.2539x; 1.2525x over previous
//
#include <hip/hip_runtime.h>
#include <hip/hip_bf16.h>
#include <math.h>

#define SEQ  512
#define BSZ  128
#define EMBD 128
#define H4   512
#define HD   128
#define NTAG 7
#define BOSX 4
#define EOSX 5
#define NEGC (-10000.0f)

typedef _Float16 h2 __attribute__((ext_vector_type(2)));
typedef _Float16 f16x8 __attribute__((ext_vector_type(8)));
typedef float    f32x4 __attribute__((ext_vector_type(4)));

__device__ __forceinline__ float frcp(float x) { return __builtin_amdgcn_rcpf(x); }

// f16 dot2: 2 MACs/inst, fp32 accumulate (v_dot2_f32_f16)
__device__ __forceinline__ float fdot2(h2 a, h2 b, float c) {
#if __has_builtin(__builtin_amdgcn_fdot2)
    return __builtin_amdgcn_fdot2(a, b, c, false);
#else
    return c + (float)a.x * (float)b.x + (float)a.y * (float)b.y;
#endif
}

template<int C> __device__ __forceinline__ float dppaddf(float x) {
    const int y = __builtin_amdgcn_update_dpp(0, __builtin_bit_cast(int, x), C, 0xF, 0xF, true);
    return x + __builtin_bit_cast(float, y);
}
template<int C> __device__ __forceinline__ float dppmovf(float x) {
    return __builtin_bit_cast(float,
        __builtin_amdgcn_update_dpp(0, __builtin_bit_cast(int, x), C, 0xF, 0xF, true));
}
template<int C> __device__ __forceinline__ int dppmovi(int x) {
    return __builtin_amdgcn_update_dpp(0, x, C, 0xF, 0xF, true);
}
// k = lane bits {0,1}: full k-reduce = 2 DPP stages
__device__ __forceinline__ float kreduce4(float x) {
    x = dppaddf<0xB1>(x);   // xor bit0
    x = dppaddf<0x4E>(x);   // xor bit1
    return x;
}

// f16 chunk layout for h (recurrence dot operand): chunk k = 32 f16 = 16
// dwords at dword offset 20*k; conflict-free b128 reads (see round-1 notes).
#define CH_DW  20
#define ROW_DW 80

// 32-element f16 chunk dot: w[16] half2 x x[16] half2 -> fp32
__device__ __forceinline__ float dot32h(const h2* __restrict__ w, const h2* __restrict__ x) {
    float a = 0.f;
    #pragma unroll
    for (int j = 0; j < 16; ++j) a = fdot2(w[j], x[j], a);
    return a;
}
// load 32 fp32 weights -> 16 half2 (RNE, one-time)
__device__ __forceinline__ void ldwh(h2* w, const float4* wr) {
    #pragma unroll
    for (int j = 0; j < 8; ++j) {
        const float4 f4 = wr[j];
        h2 a; a.x = (_Float16)f4.x; a.y = (_Float16)f4.y;
        h2 b; b.x = (_Float16)f4.z; b.y = (_Float16)f4.w;
        w[2 * j] = a; w[2 * j + 1] = b;
    }
}
__device__ __forceinline__ void unp16(const uint4* p, h2* x) {
    #pragma unroll
    for (int j = 0; j < 4; ++j) {
        x[4 * j]     = __builtin_bit_cast(h2, p[j].x);
        x[4 * j + 1] = __builtin_bit_cast(h2, p[j].y);
        x[4 * j + 2] = __builtin_bit_cast(h2, p[j].z);
        x[4 * j + 3] = __builtin_bit_cast(h2, p[j].w);
    }
}

// =============== K1: FUSED recurrence + MFMA-batched projection ==============
// Round-1 structure, but the per-step per-lane 64-fdot2 projection (half the
// per-step VALU, the measured 66%-VALUBusy bottleneck) is replaced by a
// once-per-8-steps MFMA batch: z[rows base+8..15][512 gate-rows] =
// x[8x128] * Wih^T via 16 x mfma_f32_16x16x32_f16 per wave, results + bias
// to a 32KB LDS z-double-buffer; per-step consumption = one ds_read_b32.
// All MFMA fragment layouts are copied from the round-2 kernel which PASSED
// refcheck (A: [ks][kg][row][8], lane reads (kg=lane>>4,row=lane&15); B per
// gate-row R=(wid*4+tt)*16+col; D: col=lane&15=N, row=(lane>>4)*4+reg=M).
// Wih B-frags are MFMA operands -> AGPR-native if the allocator overflows
// the 128-VGPR budget (no v_accvgpr shuttling on the projection path).
// Recurrence / cell / emission / h chunk-layout unchanged from round 1.
__global__ __launch_bounds__(512) __attribute__((amdgpu_waves_per_eu(1, 2)))
void bilstm_fused(const int* __restrict__ sen, const float* __restrict__ emb,
                  const float* __restrict__ Wih_f, const float* __restrict__ b_f,
                  const float* __restrict__ Wih_b, const float* __restrict__ b_b,
                  const float* __restrict__ Whh_f, const float* __restrict__ Whh_b,
                  const float* __restrict__ W_out,
                  float* __restrict__ eft, float* __restrict__ ebt)
{
    const int tid = threadIdx.x;
    const int wid = tid >> 6;
    const int lane = tid & 63;
    const int k = lane & 3;                                // K-chunk / owned gate q
    const int m = lane >> 2;                               // 0..15
    const int u = wid * 16 + m;
    const bool bk0 = (lane & 1) != 0;
    const bool bk1 = (lane & 2) != 0;
    const int col = lane & 15;                             // MFMA N-col / A-row
    const int kg  = lane >> 4;                             // MFMA K-group
    const int chain = blockIdx.x;
    const int dir = chain & 1;
    const int b = chain >> 1;
    const int t0 = dir ? (SEQ - 1) : 0;
    const int ts = dir ? -1 : 1;

    __shared__ __align__(16) _Float16 xA[2][4][4][16][8];  // x A-frag dbuf, 8 KB
    __shared__ __align__(16) float zb[2][8][512];          // z (proj+bias) dbuf, 32 KB
    __shared__ __align__(16) unsigned hdb_u[2 * ROW_DW];   // h double-buffer, f16 chunks

    const float* __restrict__ Wih  = dir ? Wih_b : Wih_f;
    const float* __restrict__ Whh  = dir ? Whh_b : Whh_f;
    const float* __restrict__ bias = dir ? b_b  : b_f;

    // recurrence weights (dot layout) + emission weights
    h2 whh[4][16], wo[16];
    #pragma unroll
    for (int g = 0; g < 4; ++g)
        ldwh(whh[g], (const float4*)(Whh + (g * HD + u) * HD + k * 32));
    {
        const int mm = (m < NTAG) ? m : 0;
        ldwh(wo, (const float4*)(W_out + mm * 256 + dir * HD + k * 32));
    }
    // projection weights as MFMA B-fragments: tile tt covers gate-rows
    // R=(wid*4+tt)*16+col; frag ks holds k = ks*32 + kg*8 + j  [round-2-verified]
    f16x8 bw[4][4];
    float biasv[4];
    #pragma unroll
    for (int tt = 0; tt < 4; ++tt) {
        const int R = (wid * 4 + tt) * 16 + col;
        const int ug = R >> 2;
        const int gg = R & 3;
        #pragma unroll
        for (int ks = 0; ks < 4; ++ks) {
            const float* src = Wih + (gg * HD + ug) * EMBD + ks * 32 + kg * 8;
            f16x8 v;
            #pragma unroll
            for (int j = 0; j < 8; ++j) v[j] = (_Float16)src[j];
            bw[tt][ks] = v;
        }
        biasv[tt] = bias[gg * HD + ug];
    }

    if (tid < 2 * ROW_DW) hdb_u[tid] = 0u;                 // h=0
    {   // zero xA (rows 8..15 never staged; keep MFMA inputs finite)
        unsigned* p = (unsigned*)xA;                       // 2048 dwords
        p[tid] = 0u; p[tid + 512] = 0u; p[tid + 1024] = 0u; p[tid + 1536] = 0u;
    }

    // ---- x staging: window w = rows [8w,8w+8); wave srow stages row 8w+srow,
    // lane sp loads float2 (k=2sp) -> one dword of the A-frag layout:
    // ks=sp>>4, kg=(sp>>2)&3, j=(sp&3)*2  (k = 32ks+8kg+j = 2sp exactly) ----
    const int srow = wid;
    const int sp = lane;
    float2 sv;                                             // in-flight window regs
    auto sissue = [&](int w) {
        const int row = w * 8 + srow;
        const int tg = t0 + ts * row;
        const int tok = sen[tg * BSZ + b];
        sv = *(const float2*)(emb + (size_t)tok * EMBD + 2 * sp);
    };
    auto swrite = [&](int buf) {
        h2 t; t.x = (_Float16)sv.x; t.y = (_Float16)sv.y;
        *(unsigned*)&xA[buf][sp >> 4][(sp >> 2) & 3][srow][(sp & 3) * 2]
            = __builtin_bit_cast(unsigned, t);
    };

    // ---- batched projection: 16 MFMA -> z rows 0..7 of buffer nb ----
    auto proj = [&](int bufp, int nb) {
        f16x8 ax[4];
        #pragma unroll
        for (int ks = 0; ks < 4; ++ks)
            ax[ks] = *(const f16x8*)&xA[bufp][ks][kg][col][0];
        f32x4 acc[4];
        #pragma unroll
        for (int tt = 0; tt < 4; ++tt) { acc[tt][0]=0.f; acc[tt][1]=0.f; acc[tt][2]=0.f; acc[tt][3]=0.f; }
        #pragma unroll
        for (int ks = 0; ks < 4; ++ks)
            #pragma unroll
            for (int tt = 0; tt < 4; ++tt)
                acc[tt] = __builtin_amdgcn_mfma_f32_16x16x32_f16(ax[ks], bw[tt][ks], acc[tt], 0, 0, 0);
        if (lane < 32) {                                   // D rows 0..7 = time rows
            #pragma unroll
            for (int tt = 0; tt < 4; ++tt)
                #pragma unroll
                for (int r = 0; r < 4; ++r)
                    zb[nb][(lane >> 4) * 4 + r][wid * 64 + tt * 16 + col]
                        = acc[tt][r] + biasv[tt];
        }
    };

    float c = 0.0f, v0 = 0.0f, v1 = 0.0f, v2 = 0.0f, v3 = 0.0f;
    float* __restrict__ eX = (dir ? ebt : eft) + (size_t)b * (SEQ * 8);

    // ---- prologue: stage windows 0,1; proj window0 -> zb[0]; window 2 in flight
    sissue(0); swrite(0);
    sissue(1); swrite(1);
    __syncthreads();
    proj(0, 0);                                            // z rows 0..7
    sissue(2);
    __syncthreads();

    // ---- main loop: 64 blocks of 8 steps ----
    for (int base = 0; base < SEQ; base += 8) {
        const int W = base >> 3;
        #pragma unroll
        for (int sl = 0; sl < 8; ++sl) {
            const int s = base + sl;
            const int cur = sl & 1;                        // base even -> s&1 == sl&1
            // h-read for this step (chunk k of h_{t-ts})
            uint4 hpk[4];
            {
                const uint4* hr = (const uint4*)(hdb_u + cur * ROW_DW + k * CH_DW);
                #pragma unroll
                for (int j = 0; j < 4; ++j) hpk[j] = hr[j];
            }
            if (sl == 0) {
                if (base <= SEQ - 24) swrite(W & 1);       // window W+2 -> buf W&1
                if (base <= SEQ - 32) sissue(W + 3);       // rows [base+24,base+32)
                // proj rows base+8..15 (window W+1, buf (W&1)^1) -> zb[(W&1)^1]
                if (W < 63) proj((W & 1) ^ 1, (W & 1) ^ 1);
            }
            const float xq = zb[W & 1][sl][wid * 64 + lane];   // z for THIS step
            // recurrence
            h2 hx[16];
            unp16(hpk, hx);
            {
                const float pi = dot32h(whh[0], hx);
                const float pf = dot32h(whh[1], hx);
                const float pg = dot32h(whh[2], hx);
                const float po = dot32h(whh[3], hx);
                const float A = (bk0 ? pf : pi) + dppmovf<0xB1>(bk0 ? pi : pf);
                const float B = (bk0 ? po : pg) + dppmovf<0x4E>(bk0 ? pg : po);
                float z = (bk1 ? B : A) + dppmovf<0x4E>(bk1 ? A : B);
                z += xq;
                // one activation per lane (gate 2 = tanh via 2*sigma(2z)-1)
                const bool isg = bk1 && !bk0;
                const float x2 = isg ? (z + z) : z;
                float y = frcp(1.0f + __expf(-x2));
                y = isg ? (2.0f * y - 1.0f) : y;
                // all-gather the 4 activated gates
                const float r1 = dppmovf<0xB1>(y);
                const float r2 = dppmovf<0x4E>(y);
                const float r3 = dppmovf<0x4E>(r1);
                const float i0 = bk0 ? r1 : y,  i1 = bk0 ? y : r1;
                const float i2 = bk0 ? r3 : r2, i3 = bk0 ? r2 : r3;
                const float gi = bk1 ? i2 : i0;
                const float gf = bk1 ? i3 : i1;
                const float gg2 = bk1 ? i0 : i2;
                const float go = bk1 ? i1 : i3;
                c = gf * c + gi * gg2;                     // redundant across 4 k-lanes
                const float th = 2.0f * frcp(1.0f + __expf(-2.0f * c)) - 1.0f;
                const float h = go * th;
                if (k == 0) {                              // write h as f16 halfword
                    ((unsigned short*)hdb_u)[((cur ^ 1) * ROW_DW + (u >> 5) * CH_DW) * 2 + (u & 31)]
                        = __builtin_bit_cast(unsigned short, (_Float16)h);
                }
            }
            if (wid == 0 && s >= 1) {                      // emission for time e = s-1
                const float ev = kreduce4(dot32h(wo, hx));
                const int e = s - 1;
                const bool mine = (e & 3) == k;            // e uniform, k lane-varying
                const int j = (e >> 2) & 3;
                v0 = (mine && j == 0) ? ev : v0;
                v1 = (mine && j == 1) ? ev : v1;
                v2 = (mine && j == 2) ? ev : v2;
                v3 = (mine && j == 3) ? ev : v3;
                if ((s & 15) == 0 && m < NTAG) {           // flush e in [s-16, s-1]
                    const int eA = s - 16 + k;
                    eX[(t0 + ts * (eA +  0)) * 8 + m] = v0;
                    eX[(t0 + ts * (eA +  4)) * 8 + m] = v1;
                    eX[(t0 + ts * (eA +  8)) * 8 + m] = v2;
                    eX[(t0 + ts * (eA + 12)) * 8 + m] = v3;
                }
            }
            __syncthreads();
        }
    }

    // ---- epilogue: s = SEQ -> emission e = SEQ-1 + final flush ----
    {
        h2 hx[16];                                         // h_{last} from hdb[0]
        const uint4* hr = (const uint4*)(hdb_u + k * CH_DW);
        uint4 pk[4];
        #pragma unroll
        for (int j = 0; j < 4; ++j) pk[j] = hr[j];
        unp16(pk, hx);
        if (wid == 0) {
            const float ev = kreduce4(dot32h(wo, hx));
            if (k == 3) v3 = ev;                           // e=511: (e&3)=3, (e>>2)&3=3
            if (m < NTAG) {
                const int eA = SEQ - 16 + k;
                eX[(t0 + ts * (eA +  0)) * 8 + m] = v0;
                eX[(t0 + ts * (eA +  4)) * 8 + m] = v1;
                eX[(t0 + ts * (eA +  8)) * 8 + m] = v2;
                eX[(t0 + ts * (eA + 12)) * 8 + m] = v3;
            }
        }
    }
}

// ======================= K2: Viterbi scan + backtrace =======================
// (verbatim round-4 kernel: DPP butterfly argmax, OR-packed 3-bit
// backpointer words, readlane-only bit-chase backtrace)
__global__ __launch_bounds__(256, 1)
void vit_kernel(const float* __restrict__ eft, const float* __restrict__ ebt,
                const float* __restrict__ b_out, const float* __restrict__ trans,
                float* __restrict__ out)
{
    const int b = blockIdx.x;
    const int tid = threadIdx.x;
    __shared__ __align__(16) float ftl[SEQ * 8];
    __shared__ unsigned wordL[SEQ];                        // packed backpointers

    {   // stage ef+eb with all 256 threads
        const float4* sf = (const float4*)(eft + (size_t)b * (SEQ * 8));
        const float4* sb = (const float4*)(ebt + (size_t)b * (SEQ * 8));
        float4* dst = (float4*)ftl;
        #pragma unroll
        for (int i = 0; i < SEQ * 2 / 256; ++i) {
            const int idx = tid + i * 256;
            float4 a = sf[idx];
            const float4 c4 = sb[idx];
            a.x += c4.x; a.y += c4.y; a.z += c4.z; a.w += c4.w;
            dst[idx] = a;
        }
    }
    __syncthreads();

    if (tid < 64) {
        const int lane = tid;
        const int next = lane >> 3;
        const int prev = lane & 7;
        const bool pv = (prev < NTAG);
        const bool nv = (next < NTAG);
        const float trv = (pv && nv) ? (trans[next * NTAG + prev] + b_out[next]) : -3.0e38f;
        float fvp = pv ? ((prev == BOSX) ? 0.0f : NEGC) : -3.0e38f;

        // (max, first-index) combiner is associative+commutative ->
        // any butterfly pairing gives results identical to the shfl version.
        for (int t = 0; t < SEQ; ++t) {
            float mv = fvp + trv;
            int am = prev;
            {   // xor1 (quad_perm)
                const float om = dppmovf<0xB1>(mv); const int oa = dppmovi<0xB1>(am);
                if (om > mv || (om == mv && oa < am)) { mv = om; am = oa; }
            }
            {   // xor2 (quad_perm)
                const float om = dppmovf<0x4E>(mv); const int oa = dppmovi<0x4E>(am);
                if (om > mv || (om == mv && oa < am)) { mv = om; am = oa; }
            }
            {   // quad-pair via row_half_mirror (value quad-uniform by now)
                const float om = dppmovf<0x141>(mv); const int oa = dppmovi<0x141>(am);
                if (om > mv || (om == mv && oa < am)) { mv = om; am = oa; }
            }
            const float fvnew = mv + ftl[t * 8 + next];
            // transpose: fvp[lane] = fvnew(next = prev(lane)); same pattern
            // gathers am so lane holds bptr[next = prev(lane)]
            const float nfv = __shfl(fvnew, (lane & 7) << 3);
            const int   amg = __shfl(am,    (lane & 7) << 3);
            unsigned pw = (unsigned)amg << (3 * prev);     // field for next = prev(lane)
            pw |= (unsigned)dppmovi<0xB1>((int)pw);
            pw |= (unsigned)dppmovi<0x4E>((int)pw);
            pw |= (unsigned)dppmovi<0x141>((int)pw);
            if (lane == 0) wordL[t] = pw;
            fvp = pv ? nfv : -3.0e38f;
        }

        float term = pv ? (fvp + trans[EOSX * NTAG + prev]) : -3.0e38f;
        int am = prev;
        {
            const float om = dppmovf<0xB1>(term); const int oa = dppmovi<0xB1>(am);
            if (om > term || (om == term && oa < am)) { term = om; am = oa; }
        }
        {
            const float om = dppmovf<0x4E>(term); const int oa = dppmovi<0x4E>(am);
            if (om > term || (om == term && oa < am)) { term = om; am = oa; }
        }
        {
            const float om = dppmovf<0x141>(term); const int oa = dppmovi<0x141>(am);
            if (om > term || (om == term && oa < am)) { term = om; am = oa; }
        }
        if (lane == 0) out[b] = term;

        // ---- backtrace: preload packed words, uniform readlane bit-chase ----
        unsigned wd[8];
        #pragma unroll
        for (int c2 = 0; c2 < 8; ++c2) wd[c2] = wordL[c2 * 64 + lane];
        int cur = __builtin_amdgcn_readfirstlane(am);      // uniform terminal tag
        unsigned pr[8];
        #pragma unroll
        for (int c2 = 7; c2 >= 0; --c2) {                  // unrolled: wd/pr static-indexed
            unsigned acc = 0u;
            for (int tt = 63; tt >= 0; --tt) {             // t = c2*64 + tt, descending
                acc = (lane == tt) ? (unsigned)cur : acc;  // path[t] = cur
                const unsigned w = (unsigned)__builtin_amdgcn_readlane((int)wd[c2], tt);
                cur = (int)((w >> (3 * cur)) & 7u);        // cur = bptr[t][cur]
            }
            pr[c2] = acc;
        }
        #pragma unroll
        for (int c2 = 0; c2 < 8; ++c2)
            out[BSZ + (c2 * 64 + lane) * BSZ + b] = (float)pr[c2];
    }
}

// ======================= launch =======================
extern "C" void kernel_launch(void* const* d_in, const int* in_sizes, int n_in,
                              void* d_out, int out_size, void* d_ws, size_t ws_size,
                              hipStream_t stream)
{
    const int*   sen   = (const int*)d_in[0];
    const float* emb   = (const float*)d_in[1];
    const float* Wih_f = (const float*)d_in[2];
    const float* Whh_f = (const float*)d_in[3];
    const float* b_f   = (const float*)d_in[4];
    const float* Wih_b = (const float*)d_in[5];
    const float* Whh_b = (const float*)d_in[6];
    const float* b_b   = (const float*)d_in[7];
    const float* W_out = (const float*)d_in[8];
    const float* b_out = (const float*)d_in[9];
    const float* trans = (const float*)d_in[10];
    float* out = (float*)d_out;

    char* ws = (char*)d_ws;
    const size_t ft_bytes = (size_t)BSZ * SEQ * 8 * 4;    // 2 MB each
    float* eft = (float*)ws;
    float* ebt = (float*)(ws + ft_bytes);

    bilstm_fused<<<dim3(2 * BSZ), dim3(512), 0, stream>>>(
        sen, emb, Wih_f, b_f, Wih_b, b_b, Whh_f, Whh_b, W_out, eft, ebt);
    vit_kernel<<<dim3(BSZ), dim3(256), 0, stream>>>(eft, ebt, b_out, trans, out);
}